// Round 6
// baseline (8903.786 us; speedup 1.0000x reference)
//
#include <hip/hip_runtime.h>
#include <cstdint>
#include <cstddef>

// Problem constants
#define BB 32
#define TT 2048
#define DD 256
#define HH 256
#define CC 128
#define GG 512   // 2*H

// ---------- bf16 helpers ----------
#if defined(__has_builtin)
#  if __has_builtin(__builtin_amdgcn_fdot2_f32_bf16)
#    define HAVE_BF16_DOT2 1
#  endif
#endif
#ifndef HAVE_BF16_DOT2
#  define HAVE_BF16_DOT2 0
#endif

#if HAVE_BF16_DOT2
typedef __bf16 bf16x2_t __attribute__((ext_vector_type(2)));
#endif

__device__ __forceinline__ float bflo(uint32_t w) { return __uint_as_float(w << 16); }
__device__ __forceinline__ float bfhi(uint32_t w) { return __uint_as_float(w & 0xffff0000u); }

__device__ __forceinline__ float dot2bf(uint32_t w, uint32_t h, float acc) {
#if HAVE_BF16_DOT2
  return __builtin_amdgcn_fdot2_f32_bf16(__builtin_bit_cast(bf16x2_t, w),
                                         __builtin_bit_cast(bf16x2_t, h),
                                         acc, false);
#else
  acc = fmaf(bflo(w), bflo(h), acc);
  acc = fmaf(bfhi(w), bfhi(h), acc);
  return acc;
#endif
}

__device__ __forceinline__ uint16_t f2bf(float x) {
  uint32_t u = __float_as_uint(x);
  uint32_t r = (u + 0x7fffu + ((u >> 16) & 1u)) >> 16;
  return (uint16_t)r;
}

__device__ __forceinline__ uint32_t pkbf(float a, float b) {
  return (uint32_t)f2bf(a) | ((uint32_t)f2bf(b) << 16);
}

__device__ __forceinline__ float sigm(float x) { return 1.f / (1.f + __expf(-x)); }
__device__ __forceinline__ float tanh_f(float x) {
  float e = __expf(-2.f * fabsf(x));
  float t = (1.f - e) / (1.f + e);
  return copysignf(t, x);
}

// ---------- K0: prep (also zeroes the cross-CU flags every launch) ----------
__global__ void prep_kernel(const float* __restrict__ Wg, const float* __restrict__ bg,
                            const float* __restrict__ Wc, const float* __restrict__ bc,
                            const float* __restrict__ Wp,
                            float* __restrict__ Bm, float* __restrict__ bias,
                            uint32_t* __restrict__ Whg2, uint32_t* __restrict__ Whc2,
                            uint32_t* __restrict__ Wp2, uint32_t* __restrict__ fh) {
  int i = blockIdx.x * 256 + threadIdx.x;
  if (i < 196608) {                       // Bm: [256][768] combined input weights
    int k = i / 768, n = i % 768;
    Bm[i] = (n < GG) ? Wg[k * GG + n] : Wc[k * HH + (n - GG)];
    return;
  }
  int j = i - 196608;
  if (j < 768) {                          // bias[768]
    bias[j] = (j < GG) ? bg[j] : bc[j - GG];
    return;
  }
  int a = i - 197376;
  if (a < 65536) {                        // Whg2[k2*512+j]
    int k2 = a >> 9, jj = a & 511;
    Whg2[a] = pkbf(Wg[(DD + 2 * k2) * GG + jj], Wg[(DD + 2 * k2 + 1) * GG + jj]);
    return;
  }
  int c2 = i - 262912;
  if (c2 < 32768) {                       // Whc2[k2*256+j]
    int k2 = c2 >> 8, jj = c2 & 255;
    Whc2[c2] = pkbf(Wc[(DD + 2 * k2) * HH + jj], Wc[(DD + 2 * k2 + 1) * HH + jj]);
    return;
  }
  int p2 = i - 295680;
  if (p2 < 16384) {                       // Wp2[k2*128+j]
    int k2 = p2 >> 7, jj = p2 & 127;
    Wp2[p2] = pkbf(Wp[(2 * k2) * CC + jj], Wp[(2 * k2 + 1) * CC + jj]);
    return;
  }
  int f = i - 312064;
  if (f < 2048) fh[f] = 0u;               // sync flags -> 0 (d_ws is 0xAA-poisoned)
}

// ---------- K1: input GEMM  gxc[65536][768] = x[65536][256] @ Bm[256][768] + bias ----------
__global__ __launch_bounds__(256) void gemm_in(const float* __restrict__ A,
                                               const float* __restrict__ Bm,
                                               const float* __restrict__ bias,
                                               float* __restrict__ Cm) {
  __shared__ __align__(16) float As[16][65];
  __shared__ __align__(16) float Bs[16][64];
  const int tidx = threadIdx.x;
  const int tx = tidx & 15;
  const int ty = tidx >> 4;
  const int m0 = blockIdx.y * 64;
  const int n0 = blockIdx.x * 64;
  float acc[4][4] = {};

  for (int k0 = 0; k0 < DD; k0 += 16) {
    {
      int rr = tidx >> 2;
      int c = (tidx & 3) * 4;
      float4 av = *(const float4*)(A + (size_t)(m0 + rr) * DD + k0 + c);
      As[c + 0][rr] = av.x; As[c + 1][rr] = av.y; As[c + 2][rr] = av.z; As[c + 3][rr] = av.w;
    }
    {
      int rr = tidx >> 6;
      int cc = tidx & 63;
      #pragma unroll
      for (int i = 0; i < 4; i++)
        Bs[rr + i * 4][cc] = Bm[(size_t)(k0 + rr + i * 4) * 768 + n0 + cc];
    }
    __syncthreads();
    #pragma unroll
    for (int kk = 0; kk < 16; kk++) {
      float a[4], bb[4];
      #pragma unroll
      for (int i = 0; i < 4; i++) a[i] = As[kk][ty * 4 + i];
      #pragma unroll
      for (int jj = 0; jj < 4; jj++) bb[jj] = Bs[kk][tx * 4 + jj];
      #pragma unroll
      for (int i = 0; i < 4; i++)
        #pragma unroll
        for (int jj = 0; jj < 4; jj++)
          acc[i][jj] = fmaf(a[i], bb[jj], acc[i][jj]);
    }
    __syncthreads();
  }
  float4 bv = *(const float4*)&bias[n0 + tx * 4];
  #pragma unroll
  for (int i = 0; i < 4; i++) {
    int m = m0 + ty * 4 + i;
    float4 o;
    o.x = acc[i][0] + bv.x; o.y = acc[i][1] + bv.y;
    o.z = acc[i][2] + bv.z; o.w = acc[i][3] + bv.w;
    *(float4*)(Cm + (size_t)m * 768 + n0 + tx * 4) = o;
  }
}

// ---------- K2: group-of-4-CUs scan. Block i: batch=i&31, rank=i>>5.  ----------
// Each rank: ALL r-gates (redundant), u/cand/proj column slices. One h exchange/step.
__global__ __launch_bounds__(512, 2) void rnn_scan_g4(
    const float* __restrict__ gxc,
    const uint32_t* __restrict__ Whg2,
    const uint32_t* __restrict__ Whc2,
    const uint32_t* __restrict__ Wp2,
    const float* __restrict__ bproj,
    float* __restrict__ out,
    uint32_t* __restrict__ h_x,     // [2][32][128] packed bf16 pairs
    uint32_t* __restrict__ fh) {    // [32][4][16] monotone flags
  __shared__ __align__(16) uint32_t s_h2[128];
  __shared__ __align__(16) uint32_t s_rh2[128];
  __shared__ __align__(16) float s_pr[4][256];
  __shared__ __align__(16) float s_pu[8][64];
  __shared__ __align__(16) float s_pp[16][32];
  __shared__ __align__(16) float s_pc[8][64];
  __shared__ __align__(16) float s_u[64];
  __shared__ __align__(16) float s_hfl[64];

  const int bid = blockIdx.x;
  const int b = bid & 31;
  const int r = bid >> 5;            // rank 0..3
  const int tid = threadIdx.x;

  const int jpr  = tid & 127;        // r col-pair: cols {2jpr, 2jpr+1}
  const int ksp4 = tid >> 7;         // gate k-window [32*ksp4, +32) in k2 units
  const int ju   = tid & 63;         // u col (local), abs 256+64r+ju
  const int ksp8 = tid >> 6;         // 0..7; u window [16*ksp8,+16)
  const int u2   = ksp8 & 1;
  const int jp   = tid & 31;         // proj col (local), abs 32r+jp
  const int ksp16 = tid >> 5;        // 0..15; proj window [8*ksp16,+8)
  const int m4   = ksp16 & 3;

  // ---- weights to registers (static indices) ----
  uint32_t wr0[32], wr1[32];
  #pragma unroll
  for (int i = 0; i < 32; i++) {
    wr0[i] = Whg2[(32 * ksp4 + i) * 512 + 2 * jpr];
    wr1[i] = Whg2[(32 * ksp4 + i) * 512 + 2 * jpr + 1];
  }
  uint32_t wu[16];
  #pragma unroll
  for (int i = 0; i < 16; i++) wu[i] = Whg2[(16 * ksp8 + i) * 512 + 256 + 64 * r + ju];
  uint32_t wc[16];
  #pragma unroll
  for (int i = 0; i < 16; i++) wc[i] = Whc2[(16 * ksp8 + i) * 256 + 64 * r + ju];
  uint32_t wp[8];
  #pragma unroll
  for (int i = 0; i < 8; i++) wp[i] = Wp2[(8 * ksp16 + i) * 128 + 32 * r + jp];

  if (tid < 128) s_h2[tid] = 0u;
  if (tid < 64) s_hfl[tid] = 0.f;

  const float* gx_b = gxc + (size_t)b * TT * 768;
  float* out_b = out + (size_t)b * TT * CC;
  const float bpv = (tid >= 192 && tid < 224) ? bproj[32 * r + (tid - 192)] : 0.f;

  __syncthreads();

  for (int t = 0; t <= TT; t++) {
    const int tg = (t < TT) ? t : (TT - 1);          // clamp input index
    const float* gx_t = gx_b + (size_t)tg * 768;

    // prefetch this step's streaming inputs
    float gxr0 = 0.f, gxr1 = 0.f, gxu = 0.f, cx0 = 0.f, cx1 = 0.f;
    if (tid < 128) {
      float2 gp = *(const float2*)&gx_t[2 * tid];
      gxr0 = gp.x; gxr1 = gp.y;
      if (tid < 32) {
        float2 cp = *(const float2*)&gx_t[GG + 64 * r + 2 * tid];
        cx0 = cp.x; cx1 = cp.y;
      }
    } else if (tid < 192) {
      gxu = gx_t[256 + 64 * r + (tid - 128)];
    }

    // ---- phase A: r/u-gate + proj(t-1) partials, all sharing the h quads ----
    float ar0 = 0.f, ar1 = 0.f, au = 0.f, ap = 0.f;
    #pragma unroll
    for (int i2 = 0; i2 < 8; i2++) {
      uint4 hq = *(const uint4*)&s_h2[32 * ksp4 + 4 * i2];
      ar0 = dot2bf(wr0[4 * i2 + 0], hq.x, ar0);
      ar0 = dot2bf(wr0[4 * i2 + 1], hq.y, ar0);
      ar0 = dot2bf(wr0[4 * i2 + 2], hq.z, ar0);
      ar0 = dot2bf(wr0[4 * i2 + 3], hq.w, ar0);
      ar1 = dot2bf(wr1[4 * i2 + 0], hq.x, ar1);
      ar1 = dot2bf(wr1[4 * i2 + 1], hq.y, ar1);
      ar1 = dot2bf(wr1[4 * i2 + 2], hq.z, ar1);
      ar1 = dot2bf(wr1[4 * i2 + 3], hq.w, ar1);
      if ((i2 >> 2) == u2) {                      // wave-uniform branch
        au = dot2bf(wu[4 * (i2 & 3) + 0], hq.x, au);
        au = dot2bf(wu[4 * (i2 & 3) + 1], hq.y, au);
        au = dot2bf(wu[4 * (i2 & 3) + 2], hq.z, au);
        au = dot2bf(wu[4 * (i2 & 3) + 3], hq.w, au);
      }
      if (2 * m4 == i2) {                         // half-wave divergent, tiny
        ap = dot2bf(wp[0], hq.x, ap);
        ap = dot2bf(wp[1], hq.y, ap);
        ap = dot2bf(wp[2], hq.z, ap);
        ap = dot2bf(wp[3], hq.w, ap);
      } else if (2 * m4 + 1 == i2) {
        ap = dot2bf(wp[4], hq.x, ap);
        ap = dot2bf(wp[5], hq.y, ap);
        ap = dot2bf(wp[6], hq.z, ap);
        ap = dot2bf(wp[7], hq.w, ap);
      }
    }
    *(float2*)&s_pr[ksp4][2 * jpr] = make_float2(ar0, ar1);
    s_pu[ksp8][ju] = au;
    s_pp[ksp16][jp] = ap;
    __syncthreads();   // B1

    // ---- reduces ----
    if (tid < 128) {
      float v0 = s_pr[0][2 * tid] + s_pr[1][2 * tid] + s_pr[2][2 * tid] + s_pr[3][2 * tid] + gxr0;
      float v1 = s_pr[0][2 * tid + 1] + s_pr[1][2 * tid + 1] + s_pr[2][2 * tid + 1] + s_pr[3][2 * tid + 1] + gxr1;
      float r0 = sigm(v0), r1 = sigm(v1);
      uint32_t hw = s_h2[tid];
      s_rh2[tid] = pkbf(r0 * bflo(hw), r1 * bfhi(hw));
    } else if (tid < 192) {
      int j = tid - 128;
      float a = gxu;
      #pragma unroll
      for (int k = 0; k < 8; k++) a += s_pu[k][j];
      s_u[j] = sigm(a);
    } else if (tid < 224 && t > 0) {
      int j = tid - 192;
      float a = bpv;
      #pragma unroll
      for (int k = 0; k < 16; k++) a += s_pp[k][j];
      out_b[(size_t)(t - 1) * CC + 32 * r + j] = sigm(a);
    }
    __syncthreads();   // B1b

    if (t == TT) break;

    // ---- cand partials ----
    {
      float ac = 0.f;
      #pragma unroll
      for (int i2 = 0; i2 < 4; i2++) {
        uint4 rq = *(const uint4*)&s_rh2[16 * ksp8 + 4 * i2];
        ac = dot2bf(wc[4 * i2 + 0], rq.x, ac);
        ac = dot2bf(wc[4 * i2 + 1], rq.y, ac);
        ac = dot2bf(wc[4 * i2 + 2], rq.z, ac);
        ac = dot2bf(wc[4 * i2 + 3], rq.w, ac);
      }
      s_pc[ksp8][ju] = ac;
    }
    __syncthreads();   // B2

    // ---- combine + h exchange ----
    if (tid < 32) {
      int c0 = 2 * tid, c1 = 2 * tid + 1;
      float a0 = cx0, a1 = cx1;
      #pragma unroll
      for (int k = 0; k < 8; k++) { a0 += s_pc[k][c0]; a1 += s_pc[k][c1]; }
      float cc0 = tanh_f(a0), cc1 = tanh_f(a1);
      float u0 = s_u[c0], u1 = s_u[c1];
      float h0 = s_hfl[c0], h1 = s_hfl[c1];
      float hn0 = u0 * h0 + (1.f - u0) * cc0;
      float hn1 = u1 * h1 + (1.f - u1) * cc1;
      s_hfl[c0] = hn0; s_hfl[c1] = hn1;
      uint32_t hwv = pkbf(hn0, hn1);
      __hip_atomic_store(&h_x[((size_t)(t & 1) * 32 + b) * 128 + 32 * r + tid], hwv,
                         __ATOMIC_RELAXED, __HIP_MEMORY_SCOPE_AGENT);
    }
    if (tid == 0) {
      __builtin_amdgcn_fence(__ATOMIC_RELEASE, "agent");
      __hip_atomic_store(&fh[(b * 4 + r) * 16], (uint32_t)(t + 1),
                         __ATOMIC_RELAXED, __HIP_MEMORY_SCOPE_AGENT);
    }

    // ---- spin + gather h(t+1) ----
    if (tid < 128) {
      const uint32_t tgt = (uint32_t)(t + 1);
      uint32_t* fp = &fh[(b * 4 + (tid >> 5)) * 16];
      while (__hip_atomic_load(fp, __ATOMIC_RELAXED, __HIP_MEMORY_SCOPE_AGENT) < tgt) {}
      __builtin_amdgcn_fence(__ATOMIC_ACQUIRE, "agent");
      s_h2[tid] = __hip_atomic_load(&h_x[((size_t)(t & 1) * 32 + b) * 128 + tid],
                                    __ATOMIC_RELAXED, __HIP_MEMORY_SCOPE_AGENT);
    }
    __syncthreads();   // BS2
  }
}

// ---------- launch ----------
extern "C" void kernel_launch(void* const* d_in, const int* in_sizes, int n_in,
                              void* d_out, int out_size, void* d_ws, size_t ws_size,
                              hipStream_t stream) {
  const float* x  = (const float*)d_in[0];
  const float* Wg = (const float*)d_in[1];
  const float* bg = (const float*)d_in[2];
  const float* Wc = (const float*)d_in[3];
  const float* bc = (const float*)d_in[4];
  const float* Wp = (const float*)d_in[5];
  const float* bp = (const float*)d_in[6];
  float* out = (float*)d_out;

  // workspace carve (bytes)
  char* w = (char*)d_ws;
  float*    gxc  = (float*)   (w);                  // 201326592
  float*    Bm   = (float*)   (w + 201326592ull);   // 786432
  float*    bias = (float*)   (w + 202113024ull);   // 3072
  uint32_t* Whg2 = (uint32_t*)(w + 202116096ull);   // 262144
  uint32_t* Whc2 = (uint32_t*)(w + 202378240ull);   // 131072
  uint32_t* Wp2  = (uint32_t*)(w + 202509312ull);   // 65536
  uint32_t* h_x  = (uint32_t*)(w + 202574848ull);   // 2*32*128*4 = 32768
  uint32_t* fh   = (uint32_t*)(w + 202607616ull);   // 2048*4     = 8192
                                                    // total 202615808

  prep_kernel<<<1227, 256, 0, stream>>>(Wg, bg, Wc, bc, Wp, Bm, bias, Whg2, Whc2, Wp2, fh);
  gemm_in<<<dim3(12, 1024), 256, 0, stream>>>(x, Bm, bias, gxc);
  rnn_scan_g4<<<128, 512, 0, stream>>>(gxc, Whg2, Whc2, Wp2, bp, out, h_x, fh);
}

// Round 7
// 3720.230 us; speedup vs baseline: 2.3933x; 2.3933x over previous
//
#include <hip/hip_runtime.h>
#include <cstdint>
#include <cstddef>

// Problem constants
#define BB 32
#define TT 2048
#define DD 256
#define HH 256
#define CC 128
#define GG 512   // 2*H

// ---------- bf16 helpers ----------
#if defined(__has_builtin)
#  if __has_builtin(__builtin_amdgcn_fdot2_f32_bf16)
#    define HAVE_BF16_DOT2 1
#  endif
#endif
#ifndef HAVE_BF16_DOT2
#  define HAVE_BF16_DOT2 0
#endif

#if HAVE_BF16_DOT2
typedef __bf16 bf16x2_t __attribute__((ext_vector_type(2)));
#endif

__device__ __forceinline__ float bflo(uint32_t w) { return __uint_as_float(w << 16); }
__device__ __forceinline__ float bfhi(uint32_t w) { return __uint_as_float(w & 0xffff0000u); }

__device__ __forceinline__ float dot2bf(uint32_t w, uint32_t h, float acc) {
#if HAVE_BF16_DOT2
  return __builtin_amdgcn_fdot2_f32_bf16(__builtin_bit_cast(bf16x2_t, w),
                                         __builtin_bit_cast(bf16x2_t, h),
                                         acc, false);
#else
  acc = fmaf(bflo(w), bflo(h), acc);
  acc = fmaf(bfhi(w), bfhi(h), acc);
  return acc;
#endif
}

__device__ __forceinline__ uint16_t f2bf(float x) {
  uint32_t u = __float_as_uint(x);
  uint32_t r = (u + 0x7fffu + ((u >> 16) & 1u)) >> 16;
  return (uint16_t)r;
}

__device__ __forceinline__ uint32_t pkbf(float a, float b) {
  return (uint32_t)f2bf(a) | ((uint32_t)f2bf(b) << 16);
}

__device__ __forceinline__ float sigm(float x) { return 1.f / (1.f + __expf(-x)); }
__device__ __forceinline__ float tanh_f(float x) {
  float e = __expf(-2.f * fabsf(x));
  float t = (1.f - e) / (1.f + e);
  return copysignf(t, x);
}

// ---------- K0: prep ----------
__global__ void prep_kernel(const float* __restrict__ Wg, const float* __restrict__ bg,
                            const float* __restrict__ Wc, const float* __restrict__ bc,
                            const float* __restrict__ Wp,
                            float* __restrict__ Bm, float* __restrict__ bias,
                            uint32_t* __restrict__ Whg2, uint32_t* __restrict__ Whc2,
                            uint32_t* __restrict__ Wp2) {
  int i = blockIdx.x * 256 + threadIdx.x;
  if (i < 196608) {                       // Bm: [256][768] combined input weights
    int k = i / 768, n = i % 768;
    Bm[i] = (n < GG) ? Wg[k * GG + n] : Wc[k * HH + (n - GG)];
    return;
  }
  int j = i - 196608;
  if (j < 768) {                          // bias[768]
    bias[j] = (j < GG) ? bg[j] : bc[j - GG];
    return;
  }
  int a = i - 197376;
  if (a < 65536) {                        // Whg2[k2*512+j]
    int k2 = a >> 9, jj = a & 511;
    Whg2[a] = pkbf(Wg[(DD + 2 * k2) * GG + jj], Wg[(DD + 2 * k2 + 1) * GG + jj]);
    return;
  }
  int c2 = i - 262912;
  if (c2 < 32768) {                       // Whc2[k2*256+j]
    int k2 = c2 >> 8, jj = c2 & 255;
    Whc2[c2] = pkbf(Wc[(DD + 2 * k2) * HH + jj], Wc[(DD + 2 * k2 + 1) * HH + jj]);
    return;
  }
  int p2 = i - 295680;
  if (p2 < 16384) {                       // Wp2[k2*128+j]
    int k2 = p2 >> 7, jj = p2 & 127;
    Wp2[p2] = pkbf(Wp[(2 * k2) * CC + jj], Wp[(2 * k2 + 1) * CC + jj]);
  }
}

// ---------- K1: input GEMM  gxc[65536][768] = x[65536][256] @ Bm[256][768] + bias ----------
__global__ __launch_bounds__(256) void gemm_in(const float* __restrict__ A,
                                               const float* __restrict__ Bm,
                                               const float* __restrict__ bias,
                                               float* __restrict__ Cm) {
  __shared__ __align__(16) float As[16][65];
  __shared__ __align__(16) float Bs[16][64];
  const int tidx = threadIdx.x;
  const int tx = tidx & 15;
  const int ty = tidx >> 4;
  const int m0 = blockIdx.y * 64;
  const int n0 = blockIdx.x * 64;
  float acc[4][4] = {};

  for (int k0 = 0; k0 < DD; k0 += 16) {
    {
      int rr = tidx >> 2;
      int c = (tidx & 3) * 4;
      float4 av = *(const float4*)(A + (size_t)(m0 + rr) * DD + k0 + c);
      As[c + 0][rr] = av.x; As[c + 1][rr] = av.y; As[c + 2][rr] = av.z; As[c + 3][rr] = av.w;
    }
    {
      int rr = tidx >> 6;
      int cc = tidx & 63;
      #pragma unroll
      for (int i = 0; i < 4; i++)
        Bs[rr + i * 4][cc] = Bm[(size_t)(k0 + rr + i * 4) * 768 + n0 + cc];
    }
    __syncthreads();
    #pragma unroll
    for (int kk = 0; kk < 16; kk++) {
      float a[4], bb[4];
      #pragma unroll
      for (int i = 0; i < 4; i++) a[i] = As[kk][ty * 4 + i];
      #pragma unroll
      for (int jj = 0; jj < 4; jj++) bb[jj] = Bs[kk][tx * 4 + jj];
      #pragma unroll
      for (int i = 0; i < 4; i++)
        #pragma unroll
        for (int jj = 0; jj < 4; jj++)
          acc[i][jj] = fmaf(a[i], bb[jj], acc[i][jj]);
    }
    __syncthreads();
  }
  float4 bv = *(const float4*)&bias[n0 + tx * 4];
  #pragma unroll
  for (int i = 0; i < 4; i++) {
    int m = m0 + ty * 4 + i;
    float4 o;
    o.x = acc[i][0] + bv.x; o.y = acc[i][1] + bv.y;
    o.z = acc[i][2] + bv.z; o.w = acc[i][3] + bv.w;
    *(float4*)(Cm + (size_t)m * 768 + n0 + tx * 4) = o;
  }
}

// ---------- K2: single-CU-per-batch scan, NO projection, 192 weight regs/thread ----------
// Writes h(t) as packed bf16 into the (already consumed) cand slot of gxc.
__global__ __launch_bounds__(512) __attribute__((amdgpu_waves_per_eu(2, 2)))
void rnn_scan32(float* __restrict__ gxc,
                const uint32_t* __restrict__ Whg2,
                const uint32_t* __restrict__ Whc2) {
  __shared__ __align__(16) uint32_t s_h2[128];   // h packed bf16 k-pairs
  __shared__ __align__(16) uint32_t s_rh2[128];  // r*h packed
  __shared__ __align__(16) float s_pc[2][256];   // cand partials
  __shared__ __align__(16) float s_u[256];       // update gate
  __shared__ __align__(16) float s_hf[256];      // h f32

  const int tid = threadIdx.x;
  const int b = blockIdx.x;
  const int jc = tid & 255, kh = tid >> 8;

  // ---- weights to registers (static indices) ----
  uint32_t wg[128];
  #pragma unroll
  for (int i = 0; i < 128; i++) wg[i] = Whg2[i * 512 + tid];
  uint32_t wc[64];
  #pragma unroll
  for (int i = 0; i < 64; i++) wc[i] = Whc2[(kh * 64 + i) * 256 + jc];

  if (tid < 128) s_h2[tid] = 0u;
  if (tid < 256) s_hf[tid] = 0.f;

  float* gx_b = gxc + (size_t)b * TT * 768;
  float gv = gx_b[tid];
  float cxv = (tid < 256) ? gx_b[GG + tid] : 0.f;

  __syncthreads();

  for (int t = 0; t < TT; t++) {
    // prefetch next step's inputs (hides L2 latency under gate dot2s)
    const int tn = (t + 1 < TT) ? (t + 1) : (TT - 1);
    const float* gx_n = gx_b + (size_t)tn * 768;
    float gv_n = gx_n[tid];
    float cx_n = (tid < 256) ? gx_n[GG + tid] : 0.f;

    // ---- phase 1: gate col `tid`, full K (broadcast h quads) ----
    float acc = gv;
    #pragma unroll
    for (int k2 = 0; k2 < 128; k2 += 4) {
      uint4 hh = *(const uint4*)&s_h2[k2];
      acc = dot2bf(wg[k2 + 0], hh.x, acc);
      acc = dot2bf(wg[k2 + 1], hh.y, acc);
      acc = dot2bf(wg[k2 + 2], hh.z, acc);
      acc = dot2bf(wg[k2 + 3], hh.w, acc);
    }
    float g = sigm(acc);
    if (tid < 256) {
      ((uint16_t*)s_rh2)[tid] = f2bf(g * s_hf[tid]);   // r*h packed
    } else {
      s_u[tid - 256] = g;                               // u gate
    }
    __syncthreads();  // B1: rh + u ready

    // ---- phase 2: cand partials; thread (jc, kh) owns half the k range ----
    {
      float ac = 0.f;
      #pragma unroll
      for (int i = 0; i < 64; i += 4) {
        uint4 rq = *(const uint4*)&s_rh2[kh * 64 + i];
        ac = dot2bf(wc[i + 0], rq.x, ac);
        ac = dot2bf(wc[i + 1], rq.y, ac);
        ac = dot2bf(wc[i + 2], rq.z, ac);
        ac = dot2bf(wc[i + 3], rq.w, ac);
      }
      s_pc[kh][jc] = ac;
    }
    __syncthreads();  // B2: cand partials ready

    // ---- combine: c = tanh(cx + p0 + p1); h = u*h + (1-u)*c; write h to LDS + gxc ----
    if (tid < 256) {
      float pre = cxv + s_pc[0][tid] + s_pc[1][tid];
      float c = tanh_f(pre);
      float u = s_u[tid];
      float hf = s_hf[tid];
      float hn = u * hf + (1.f - u) * c;
      s_hf[tid] = hn;
      uint16_t hb = f2bf(hn);
      ((uint16_t*)s_h2)[tid] = hb;
      // store packed bf16 h(t) into the consumed cand area of gx(t)
      ((uint16_t*)(gx_b + (size_t)t * 768 + GG))[tid] = hb;
    }
    __syncthreads();  // B3: new h ready

    gv = gv_n; cxv = cx_n;
  }
}

// ---------- K3: output projection  out[m][c] = sigm(h_bf16[m] @ Wp + bp) ----------
// h rows read from gxc cand slots (packed bf16). Wp transposed+bank-swizzled in LDS.
__global__ __launch_bounds__(512) void proj_out(const uint32_t* __restrict__ gxcu,
                                                const uint32_t* __restrict__ Wp2,
                                                const float* __restrict__ bp,
                                                float* __restrict__ out) {
  __shared__ uint32_t s_wpT[16384];   // [col][k2], word (c,k2) at c*128 + (k2 ^ ((c&7)<<2))
  const int tid = threadIdx.x;

  #pragma unroll
  for (int i = 0; i < 8; i++) {
    int q = tid + i * 512;            // uint4 index into Wp2 [k2][128]
    uint4 v = ((const uint4*)Wp2)[q];
    int k2 = q >> 5;
    int c0 = (q & 31) * 4;
    s_wpT[(c0 + 0) * 128 + (k2 ^ (((c0 + 0) & 7) << 2))] = v.x;
    s_wpT[(c0 + 1) * 128 + (k2 ^ (((c0 + 1) & 7) << 2))] = v.y;
    s_wpT[(c0 + 2) * 128 + (k2 ^ (((c0 + 2) & 7) << 2))] = v.z;
    s_wpT[(c0 + 3) * 128 + (k2 ^ (((c0 + 3) & 7) << 2))] = v.w;
  }
  __syncthreads();

  const int col = tid & 127;
  const int rsub = tid >> 7;          // 0..3
  const float bpc = bp[col];
  const int base = blockIdx.x * 256;
  const int cswz = (col & 7) << 2;

  for (int rr = 0; rr < 64; rr++) {
    int m = base + rr * 4 + rsub;
    const uint32_t* hrow = gxcu + (size_t)m * 768 + 512;
    float acc = bpc;
    #pragma unroll 8
    for (int i2 = 0; i2 < 32; i2++) {
      uint4 hq = *(const uint4*)&hrow[4 * i2];                       // wave-uniform broadcast
      uint4 wq = *(const uint4*)&s_wpT[col * 128 + ((4 * i2) ^ cswz)];
      acc = dot2bf(wq.x, hq.x, acc);
      acc = dot2bf(wq.y, hq.y, acc);
      acc = dot2bf(wq.z, hq.z, acc);
      acc = dot2bf(wq.w, hq.w, acc);
    }
    out[(size_t)m * 128 + col] = sigm(acc);
  }
}

// ---------- launch ----------
extern "C" void kernel_launch(void* const* d_in, const int* in_sizes, int n_in,
                              void* d_out, int out_size, void* d_ws, size_t ws_size,
                              hipStream_t stream) {
  const float* x  = (const float*)d_in[0];
  const float* Wg = (const float*)d_in[1];
  const float* bg = (const float*)d_in[2];
  const float* Wc = (const float*)d_in[3];
  const float* bc = (const float*)d_in[4];
  const float* Wp = (const float*)d_in[5];
  const float* bp = (const float*)d_in[6];
  float* out = (float*)d_out;

  // workspace carve (bytes)
  char* w = (char*)d_ws;
  float*    gxc  = (float*)   (w);                  // 32*2048*768*4   = 201326592
  float*    Bm   = (float*)   (w + 201326592ull);   // 256*768*4       = 786432
  float*    bias = (float*)   (w + 202113024ull);   // 768*4           = 3072
  uint32_t* Whg2 = (uint32_t*)(w + 202116096ull);   // 128*512*4       = 262144
  uint32_t* Whc2 = (uint32_t*)(w + 202378240ull);   // 128*256*4       = 131072
  uint32_t* Wp2  = (uint32_t*)(w + 202509312ull);   // 128*128*4       = 65536
                                                    // total           = 202574848

  prep_kernel<<<1219, 256, 0, stream>>>(Wg, bg, Wc, bc, Wp, Bm, bias, Whg2, Whc2, Wp2);
  gemm_in<<<dim3(12, 1024), 256, 0, stream>>>(x, Bm, bias, gxc);
  rnn_scan32<<<BB, 512, 0, stream>>>(gxc, Whg2, Whc2);
  proj_out<<<256, 512, 0, stream>>>((const uint32_t*)gxc, Wp2, bp, out);
}

// Round 8
// 3306.222 us; speedup vs baseline: 2.6930x; 1.1252x over previous
//
#include <hip/hip_runtime.h>
#include <cstdint>
#include <cstddef>

// Problem constants
#define BB 32
#define TT 2048
#define DD 256
#define HH 256
#define CC 128
#define GG 512   // 2*H

// ---------- bf16 helpers ----------
#if defined(__has_builtin)
#  if __has_builtin(__builtin_amdgcn_fdot2_f32_bf16)
#    define HAVE_BF16_DOT2 1
#  endif
#endif
#ifndef HAVE_BF16_DOT2
#  define HAVE_BF16_DOT2 0
#endif

#if HAVE_BF16_DOT2
typedef __bf16 bf16x2_t __attribute__((ext_vector_type(2)));
#endif

__device__ __forceinline__ float bflo(uint32_t w) { return __uint_as_float(w << 16); }
__device__ __forceinline__ float bfhi(uint32_t w) { return __uint_as_float(w & 0xffff0000u); }

__device__ __forceinline__ float dot2bf(uint32_t w, uint32_t h, float acc) {
#if HAVE_BF16_DOT2
  return __builtin_amdgcn_fdot2_f32_bf16(__builtin_bit_cast(bf16x2_t, w),
                                         __builtin_bit_cast(bf16x2_t, h),
                                         acc, false);
#else
  acc = fmaf(bflo(w), bflo(h), acc);
  acc = fmaf(bfhi(w), bfhi(h), acc);
  return acc;
#endif
}

__device__ __forceinline__ uint16_t f2bf(float x) {
  uint32_t u = __float_as_uint(x);
  uint32_t r = (u + 0x7fffu + ((u >> 16) & 1u)) >> 16;
  return (uint16_t)r;
}

__device__ __forceinline__ uint32_t pkbf(float a, float b) {
  return (uint32_t)f2bf(a) | ((uint32_t)f2bf(b) << 16);
}

__device__ __forceinline__ float sigm(float x) { return 1.f / (1.f + __expf(-x)); }
__device__ __forceinline__ float tanh_f(float x) {
  float e = __expf(-2.f * fabsf(x));
  float t = (1.f - e) / (1.f + e);
  return copysignf(t, x);
}

// ---------- K0: prep ----------
__global__ void prep_kernel(const float* __restrict__ Wg, const float* __restrict__ bg,
                            const float* __restrict__ Wc, const float* __restrict__ bc,
                            const float* __restrict__ Wp,
                            float* __restrict__ Bm, float* __restrict__ bias,
                            uint32_t* __restrict__ Whg2, uint32_t* __restrict__ Whc2,
                            uint32_t* __restrict__ Wp2) {
  int i = blockIdx.x * 256 + threadIdx.x;
  if (i < 196608) {                       // Bm: [256][768] combined input weights
    int k = i / 768, n = i % 768;
    Bm[i] = (n < GG) ? Wg[k * GG + n] : Wc[k * HH + (n - GG)];
    return;
  }
  int j = i - 196608;
  if (j < 768) {                          // bias[768]
    bias[j] = (j < GG) ? bg[j] : bc[j - GG];
    return;
  }
  int a = i - 197376;
  if (a < 65536) {                        // Whg2[k2*512+j]
    int k2 = a >> 9, jj = a & 511;
    Whg2[a] = pkbf(Wg[(DD + 2 * k2) * GG + jj], Wg[(DD + 2 * k2 + 1) * GG + jj]);
    return;
  }
  int c2 = i - 262912;
  if (c2 < 32768) {                       // Whc2[k2*256+j]
    int k2 = c2 >> 8, jj = c2 & 255;
    Whc2[c2] = pkbf(Wc[(DD + 2 * k2) * HH + jj], Wc[(DD + 2 * k2 + 1) * HH + jj]);
    return;
  }
  int p2 = i - 295680;
  if (p2 < 16384) {                       // Wp2[k2*128+j]
    int k2 = p2 >> 7, jj = p2 & 127;
    Wp2[p2] = pkbf(Wp[(2 * k2) * CC + jj], Wp[(2 * k2 + 1) * CC + jj]);
  }
}

// ---------- K1: input GEMM  gxc[65536][768] = x[65536][256] @ Bm[256][768] + bias ----------
__global__ __launch_bounds__(256) void gemm_in(const float* __restrict__ A,
                                               const float* __restrict__ Bm,
                                               const float* __restrict__ bias,
                                               float* __restrict__ Cm) {
  __shared__ __align__(16) float As[16][65];
  __shared__ __align__(16) float Bs[16][64];
  const int tidx = threadIdx.x;
  const int tx = tidx & 15;
  const int ty = tidx >> 4;
  const int m0 = blockIdx.y * 64;
  const int n0 = blockIdx.x * 64;
  float acc[4][4] = {};

  for (int k0 = 0; k0 < DD; k0 += 16) {
    {
      int rr = tidx >> 2;
      int c = (tidx & 3) * 4;
      float4 av = *(const float4*)(A + (size_t)(m0 + rr) * DD + k0 + c);
      As[c + 0][rr] = av.x; As[c + 1][rr] = av.y; As[c + 2][rr] = av.z; As[c + 3][rr] = av.w;
    }
    {
      int rr = tidx >> 6;
      int cc = tidx & 63;
      #pragma unroll
      for (int i = 0; i < 4; i++)
        Bs[rr + i * 4][cc] = Bm[(size_t)(k0 + rr + i * 4) * 768 + n0 + cc];
    }
    __syncthreads();
    #pragma unroll
    for (int kk = 0; kk < 16; kk++) {
      float a[4], bb[4];
      #pragma unroll
      for (int i = 0; i < 4; i++) a[i] = As[kk][ty * 4 + i];
      #pragma unroll
      for (int jj = 0; jj < 4; jj++) bb[jj] = Bs[kk][tx * 4 + jj];
      #pragma unroll
      for (int i = 0; i < 4; i++)
        #pragma unroll
        for (int jj = 0; jj < 4; jj++)
          acc[i][jj] = fmaf(a[i], bb[jj], acc[i][jj]);
    }
    __syncthreads();
  }
  float4 bv = *(const float4*)&bias[n0 + tx * 4];
  #pragma unroll
  for (int i = 0; i < 4; i++) {
    int m = m0 + ty * 4 + i;
    float4 o;
    o.x = acc[i][0] + bv.x; o.y = acc[i][1] + bv.y;
    o.z = acc[i][2] + bv.z; o.w = acc[i][3] + bv.w;
    *(float4*)(Cm + (size_t)m * 768 + n0 + tx * 4) = o;
  }
}

// ---------- K2: scan, k-split decomposition (4 cols x K/4 per thread) ----------
// Cuts LDS h-broadcast reads 48 -> 12 per thread per step; adds cheap partial reduces.
// Writes h(t) as packed bf16 into the consumed cand slot of gxc.
__global__ __launch_bounds__(512) __attribute__((amdgpu_waves_per_eu(2, 2)))
void rnn_scan32b(float* __restrict__ gxc,
                 const uint32_t* __restrict__ Whg2,
                 const uint32_t* __restrict__ Whc2) {
  __shared__ __align__(16) uint32_t s_h2[128];    // h packed bf16 k-pairs
  __shared__ __align__(16) uint32_t s_rh2[128];   // r*h packed
  __shared__ __align__(16) float s_pg[4][512];    // gate partials [kg][col]
  __shared__ __align__(16) float s_pc[8][256];    // cand partials [kc][col]
  __shared__ __align__(16) float s_u[256];        // update gate
  __shared__ __align__(16) float s_hf[256];       // h f32

  const int tid = threadIdx.x;
  const int b = blockIdx.x;
  const int jg = tid & 127;       // gate cols 4jg..4jg+3
  const int kg = tid >> 7;        // 0..3 (wave-uniform), k2 window [32kg,+32)
  const int jc = tid & 63;        // cand cols 4jc..4jc+3
  const int kc = tid >> 6;        // 0..7 (wave-uniform), k2 window [16kc,+16)

  // ---- weights to registers (static indices only) ----
  uint32_t wg[128];   // wg[16*i4 + 4*q + c] = Whg2[(32kg + 4i4 + q)*512 + 4jg + c]
  #pragma unroll
  for (int i = 0; i < 32; i++) {
    #pragma unroll
    for (int c = 0; c < 4; c++)
      wg[4 * i + c] = Whg2[(32 * kg + i) * 512 + 4 * jg + c];
  }
  uint32_t wc[64];    // wc[16*i4 + 4*q + c] = Whc2[(16kc + 4i4 + q)*256 + 4jc + c]
  #pragma unroll
  for (int i = 0; i < 16; i++) {
    #pragma unroll
    for (int c = 0; c < 4; c++)
      wc[4 * i + c] = Whc2[(16 * kc + i) * 256 + 4 * jc + c];
  }

  if (tid < 128) s_h2[tid] = 0u;
  if (tid < 256) s_hf[tid] = 0.f;

  float* gx_b = gxc + (size_t)b * TT * 768;
  float gv = gx_b[tid];                              // gate input, col tid
  float cxv = (tid < 256) ? gx_b[GG + tid] : 0.f;    // cand input

  __syncthreads();

  for (int t = 0; t < TT; t++) {
    // prefetch next step's inputs (hides L2/L3 latency under dot2s)
    const int tn = (t + 1 < TT) ? (t + 1) : (TT - 1);
    const float* gx_n = gx_b + (size_t)tn * 768;
    float gv_n = gx_n[tid];
    float cx_n = (tid < 256) ? gx_n[GG + tid] : 0.f;

    // ---- P1: gate partials; thread (jg,kg): 4 cols, 8 h-quads ----
    {
      float a0 = 0.f, a1 = 0.f, a2 = 0.f, a3 = 0.f;
      #pragma unroll
      for (int i4 = 0; i4 < 8; i4++) {
        uint4 hh = *(const uint4*)&s_h2[32 * kg + 4 * i4];
        a0 = dot2bf(wg[16 * i4 + 0], hh.x, a0);
        a1 = dot2bf(wg[16 * i4 + 1], hh.x, a1);
        a2 = dot2bf(wg[16 * i4 + 2], hh.x, a2);
        a3 = dot2bf(wg[16 * i4 + 3], hh.x, a3);
        a0 = dot2bf(wg[16 * i4 + 4], hh.y, a0);
        a1 = dot2bf(wg[16 * i4 + 5], hh.y, a1);
        a2 = dot2bf(wg[16 * i4 + 6], hh.y, a2);
        a3 = dot2bf(wg[16 * i4 + 7], hh.y, a3);
        a0 = dot2bf(wg[16 * i4 + 8], hh.z, a0);
        a1 = dot2bf(wg[16 * i4 + 9], hh.z, a1);
        a2 = dot2bf(wg[16 * i4 + 10], hh.z, a2);
        a3 = dot2bf(wg[16 * i4 + 11], hh.z, a3);
        a0 = dot2bf(wg[16 * i4 + 12], hh.w, a0);
        a1 = dot2bf(wg[16 * i4 + 13], hh.w, a1);
        a2 = dot2bf(wg[16 * i4 + 14], hh.w, a2);
        a3 = dot2bf(wg[16 * i4 + 15], hh.w, a3);
      }
      float4 pv; pv.x = a0; pv.y = a1; pv.z = a2; pv.w = a3;
      *(float4*)&s_pg[kg][4 * jg] = pv;              // lane-contiguous b128
    }
    __syncthreads();  // B1

    // ---- P2: gate reduce (col tid) + rh/u ----
    {
      float acc = gv + s_pg[0][tid] + s_pg[1][tid] + s_pg[2][tid] + s_pg[3][tid];
      float g = sigm(acc);
      if (tid < 256) {
        ((uint16_t*)s_rh2)[tid] = f2bf(g * s_hf[tid]);   // r*h packed
      } else {
        s_u[tid - 256] = g;
      }
    }
    __syncthreads();  // B2

    // ---- P3: cand partials; thread (jc,kc): 4 cols, 4 rh-quads ----
    {
      float a0 = 0.f, a1 = 0.f, a2 = 0.f, a3 = 0.f;
      #pragma unroll
      for (int i4 = 0; i4 < 4; i4++) {
        uint4 rq = *(const uint4*)&s_rh2[16 * kc + 4 * i4];
        a0 = dot2bf(wc[16 * i4 + 0], rq.x, a0);
        a1 = dot2bf(wc[16 * i4 + 1], rq.x, a1);
        a2 = dot2bf(wc[16 * i4 + 2], rq.x, a2);
        a3 = dot2bf(wc[16 * i4 + 3], rq.x, a3);
        a0 = dot2bf(wc[16 * i4 + 4], rq.y, a0);
        a1 = dot2bf(wc[16 * i4 + 5], rq.y, a1);
        a2 = dot2bf(wc[16 * i4 + 6], rq.y, a2);
        a3 = dot2bf(wc[16 * i4 + 7], rq.y, a3);
        a0 = dot2bf(wc[16 * i4 + 8], rq.z, a0);
        a1 = dot2bf(wc[16 * i4 + 9], rq.z, a1);
        a2 = dot2bf(wc[16 * i4 + 10], rq.z, a2);
        a3 = dot2bf(wc[16 * i4 + 11], rq.z, a3);
        a0 = dot2bf(wc[16 * i4 + 12], rq.w, a0);
        a1 = dot2bf(wc[16 * i4 + 13], rq.w, a1);
        a2 = dot2bf(wc[16 * i4 + 14], rq.w, a2);
        a3 = dot2bf(wc[16 * i4 + 15], rq.w, a3);
      }
      float4 pv; pv.x = a0; pv.y = a1; pv.z = a2; pv.w = a3;
      *(float4*)&s_pc[kc][4 * jc] = pv;
    }
    __syncthreads();  // B3

    // ---- P4: combine (col tid < 256) ----
    if (tid < 256) {
      float pre = cxv;
      #pragma unroll
      for (int k = 0; k < 8; k++) pre += s_pc[k][tid];
      float c = tanh_f(pre);
      float u = s_u[tid];
      float hf = s_hf[tid];
      float hn = u * hf + (1.f - u) * c;
      s_hf[tid] = hn;
      uint16_t hb = f2bf(hn);
      ((uint16_t*)s_h2)[tid] = hb;
      ((uint16_t*)(gx_b + (size_t)t * 768 + GG))[tid] = hb;  // h(t) for proj kernel
    }
    __syncthreads();  // B4

    gv = gv_n; cxv = cx_n;
  }
}

// ---------- K3: output projection  out[m][c] = sigm(h_bf16[m] @ Wp + bp) ----------
__global__ __launch_bounds__(512) void proj_out(const uint32_t* __restrict__ gxcu,
                                                const uint32_t* __restrict__ Wp2,
                                                const float* __restrict__ bp,
                                                float* __restrict__ out) {
  __shared__ uint32_t s_wpT[16384];   // [col][k2], word (c,k2) at c*128 + (k2 ^ ((c&7)<<2))
  const int tid = threadIdx.x;

  #pragma unroll
  for (int i = 0; i < 8; i++) {
    int q = tid + i * 512;            // uint4 index into Wp2 [k2][128]
    uint4 v = ((const uint4*)Wp2)[q];
    int k2 = q >> 5;
    int c0 = (q & 31) * 4;
    s_wpT[(c0 + 0) * 128 + (k2 ^ (((c0 + 0) & 7) << 2))] = v.x;
    s_wpT[(c0 + 1) * 128 + (k2 ^ (((c0 + 1) & 7) << 2))] = v.y;
    s_wpT[(c0 + 2) * 128 + (k2 ^ (((c0 + 2) & 7) << 2))] = v.z;
    s_wpT[(c0 + 3) * 128 + (k2 ^ (((c0 + 3) & 7) << 2))] = v.w;
  }
  __syncthreads();

  const int col = tid & 127;
  const int rsub = tid >> 7;          // 0..3
  const float bpc = bp[col];
  const int base = blockIdx.x * 256;
  const int cswz = (col & 7) << 2;

  for (int rr = 0; rr < 64; rr++) {
    int m = base + rr * 4 + rsub;
    const uint32_t* hrow = gxcu + (size_t)m * 768 + 512;
    float acc = bpc;
    #pragma unroll 8
    for (int i2 = 0; i2 < 32; i2++) {
      uint4 hq = *(const uint4*)&hrow[4 * i2];                       // wave-uniform broadcast
      uint4 wq = *(const uint4*)&s_wpT[col * 128 + ((4 * i2) ^ cswz)];
      acc = dot2bf(wq.x, hq.x, acc);
      acc = dot2bf(wq.y, hq.y, acc);
      acc = dot2bf(wq.z, hq.z, acc);
      acc = dot2bf(wq.w, hq.w, acc);
    }
    out[(size_t)m * 128 + col] = sigm(acc);
  }
}

// ---------- launch ----------
extern "C" void kernel_launch(void* const* d_in, const int* in_sizes, int n_in,
                              void* d_out, int out_size, void* d_ws, size_t ws_size,
                              hipStream_t stream) {
  const float* x  = (const float*)d_in[0];
  const float* Wg = (const float*)d_in[1];
  const float* bg = (const float*)d_in[2];
  const float* Wc = (const float*)d_in[3];
  const float* bc = (const float*)d_in[4];
  const float* Wp = (const float*)d_in[5];
  const float* bp = (const float*)d_in[6];
  float* out = (float*)d_out;

  // workspace carve (bytes)
  char* w = (char*)d_ws;
  float*    gxc  = (float*)   (w);                  // 32*2048*768*4   = 201326592
  float*    Bm   = (float*)   (w + 201326592ull);   // 256*768*4       = 786432
  float*    bias = (float*)   (w + 202113024ull);   // 768*4           = 3072
  uint32_t* Whg2 = (uint32_t*)(w + 202116096ull);   // 128*512*4       = 262144
  uint32_t* Whc2 = (uint32_t*)(w + 202378240ull);   // 128*256*4       = 131072
  uint32_t* Wp2  = (uint32_t*)(w + 202509312ull);   // 128*128*4       = 65536
                                                    // total           = 202574848

  prep_kernel<<<1219, 256, 0, stream>>>(Wg, bg, Wc, bc, Wp, Bm, bias, Whg2, Whc2, Wp2);
  gemm_in<<<dim3(12, 1024), 256, 0, stream>>>(x, Bm, bias, gxc);
  rnn_scan32b<<<BB, 512, 0, stream>>>(gxc, Whg2, Whc2);
  proj_out<<<256, 512, 0, stream>>>((const uint32_t*)gxc, Wp2, bp, out);
}